// Round 4
// baseline (131.887 us; speedup 1.0000x reference)
//
#include <hip/hip_runtime.h>
#include <math.h>

// Problem dims (fixed by reference)
constexpr int B_ = 128, T_ = 512, I_ = 1024, H_ = 2048, O_ = 512;

typedef __attribute__((ext_vector_type(4))) short short4v;   // 4 bf16
typedef __attribute__((ext_vector_type(8))) short short8v;   // 8 bf16
typedef __attribute__((ext_vector_type(4))) float float4v;   // 4 f32

// f32 -> bf16 bits, round-to-nearest-even (finite inputs)
__device__ inline ushort f2bf(float f) {
    union { float f; unsigned u; } c; c.f = f;
    return (ushort)((c.u + 0x7FFF + ((c.u >> 16) & 1)) >> 16);
}

__device__ inline void mfma16(float4v& acc, short4v a, short4v b) {
    // A: row=l&15, k=4*(l>>4)+j ; B: col=l&15 ; D: col=l&15, row=4*(l>>4)+i
    asm("v_mfma_f32_16x16x16_bf16 %0, %1, %2, %0" : "+v"(acc) : "v"(a), "v"(b));
}

// ws layout: y[B*I] floats | W_comb[I*O] bf16 (as ushort)
// ---------------------------------------------------------------------------
__global__ __launch_bounds__(256) void zero_y(float* __restrict__ ws) {
    const int i = (blockIdx.x * 256 + threadIdx.x) * 4;
    *(float4v*)(ws + i) = (float4v){0.f, 0.f, 0.f, 0.f};
}

// ---------------------------------------------------------------------------
// Fused kernel:
//   blocks 0..63    : W_comb = bf16(W_in @ W_out)  [1024x512], MFMA, full-K
//   blocks 64..71   : out[r,c] = T*b_out[c] + wsum*(b_in @ W_out)[c] (broadcast)
//   blocks 72..2119 : y[b,i] += sum_t w_t x[b,t,i]  (streams x, BW-bound)
// ---------------------------------------------------------------------------
__global__ __launch_bounds__(256) void fusedA(const float* __restrict__ x,
                                              const float* __restrict__ W_in,
                                              const float* __restrict__ b_in,
                                              const float* __restrict__ W_out,
                                              const float* __restrict__ b_out,
                                              float* __restrict__ ws,
                                              float* __restrict__ out, float wsum) {
    __shared__ __align__(16) char smraw[(128 * 40 + 64 * 40) * 2];
    const int bid = blockIdx.x, tid = threadIdx.x;

    if (bid < 64) {
        // ---------------- W_comb tile [128 x 64], K = 2048 ----------------
        ushort* As = (ushort*)smraw;       // [128][40]
        ushort* Bs = As + 128 * 40;        // [64][40]
        ushort* wc = (ushort*)(ws + B_ * I_);
        const int m0 = (bid >> 3) * 128, n0 = (bid & 7) * 64;
        const int lane = tid & 63, w = tid >> 6, lo = lane & 15, hi = lane >> 4;

        float4v acc[2][4];
#pragma unroll
        for (int mf = 0; mf < 2; ++mf)
#pragma unroll
            for (int nf = 0; nf < 4; ++nf) acc[mf][nf] = (float4v){0.f, 0.f, 0.f, 0.f};

        for (int k0 = 0; k0 < H_; k0 += 32) {
            {   // A tile from W_in (stride H_)
                const int row = tid >> 1, kh = (tid & 1) * 16;
                const float* ap = W_in + (size_t)(m0 + row) * H_ + k0 + kh;
#pragma unroll
                for (int j = 0; j < 4; ++j) {
                    float4v v = *(const float4v*)(ap + 4 * j);
                    short4v s;
                    s[0] = (short)f2bf(v.x); s[1] = (short)f2bf(v.y);
                    s[2] = (short)f2bf(v.z); s[3] = (short)f2bf(v.w);
                    *(short4v*)&As[row * 40 + kh + 4 * j] = s;
                }
            }
            {   // B tile from W_out (stride O_), transposed into Bs[n][k]
                const int k = tid >> 3, nq = (tid & 7) * 8;
                const float* bp = W_out + (size_t)(k0 + k) * O_ + n0 + nq;
#pragma unroll
                for (int j = 0; j < 2; ++j) {
                    float4v v = *(const float4v*)(bp + 4 * j);
                    Bs[(nq + 4 * j + 0) * 40 + k] = f2bf(v.x);
                    Bs[(nq + 4 * j + 1) * 40 + k] = f2bf(v.y);
                    Bs[(nq + 4 * j + 2) * 40 + k] = f2bf(v.z);
                    Bs[(nq + 4 * j + 3) * 40 + k] = f2bf(v.w);
                }
            }
            __syncthreads();
#pragma unroll
            for (int ks = 0; ks < 2; ++ks) {
                const int kk = ks * 16 + 4 * hi;
                short4v a[2], bfr[4];
#pragma unroll
                for (int mf = 0; mf < 2; ++mf)
                    a[mf] = *(const short4v*)&As[(w * 32 + mf * 16 + lo) * 40 + kk];
#pragma unroll
                for (int nf = 0; nf < 4; ++nf)
                    bfr[nf] = *(const short4v*)&Bs[(nf * 16 + lo) * 40 + kk];
#pragma unroll
                for (int mf = 0; mf < 2; ++mf)
#pragma unroll
                    for (int nf = 0; nf < 4; ++nf) mfma16(acc[mf][nf], a[mf], bfr[nf]);
            }
            __syncthreads();
        }
#pragma unroll
        for (int mf = 0; mf < 2; ++mf)
#pragma unroll
            for (int nf = 0; nf < 4; ++nf)
#pragma unroll
                for (int i = 0; i < 4; ++i) {
                    const int row = w * 32 + mf * 16 + hi * 4 + i;
                    const int col = n0 + nf * 16 + lo;
                    wc[(size_t)(m0 + row) * O_ + col] = f2bf(acc[mf][nf][i]);
                }
    } else if (bid < 72) {
        // ---------------- bias vector + broadcast into out ----------------
        float* red = (float*)smraw;   // [4][64]
        float* bvl = red + 256;       // [64]
        const int bb = bid - 64, c0 = bb * 64;
        const int cl = tid & 63, sl = tid >> 6;
        const int col = c0 + cl;
        float s = 0.f;
        const float* wp = W_out + (size_t)sl * 512 * O_ + col;
        for (int h = 0; h < 512; ++h) s += b_in[sl * 512 + h] * wp[(size_t)h * O_];
        red[sl * 64 + cl] = s;
        __syncthreads();
        if (tid < 64) {
            float tot = red[tid] + red[64 + tid] + red[128 + tid] + red[192 + tid];
            bvl[tid] = (float)T_ * b_out[c0 + tid] + wsum * tot;
        }
        __syncthreads();
        const float val = bvl[cl];
        for (int r = sl; r < B_; r += 4) out[(size_t)r * O_ + col] = val;
    } else {
        // ---------------- wreduce: stream x ----------------
        float* wl = (float*)smraw;    // [32]
        const int wb = bid - 72;
        const int b = wb >> 4, tc = wb & 15, t0 = tc * 32;
        if (tid < 32)
            wl[tid] = (1.f - powf(0.9f, (float)(T_ - (t0 + tid)))) * 10.f;
        __syncthreads();
        const int i = tid * 4;
        const float* xp = x + (size_t)b * T_ * I_ + (size_t)t0 * I_ + i;
        float4v acc = {0.f, 0.f, 0.f, 0.f};
#pragma unroll
        for (int tb = 0; tb < 32; tb += 8) {
            float4v v[8];
#pragma unroll
            for (int j = 0; j < 8; ++j)
                v[j] = __builtin_nontemporal_load((const float4v*)(xp + (size_t)(tb + j) * I_));
#pragma unroll
            for (int j = 0; j < 8; ++j) {
                const float wt = wl[tb + j];
                acc.x += wt * v[j].x; acc.y += wt * v[j].y;
                acc.z += wt * v[j].z; acc.w += wt * v[j].w;
            }
        }
        float* yp = ws + b * I_ + i;
        atomicAdd(yp + 0, acc.x);
        atomicAdd(yp + 1, acc.y);
        atomicAdd(yp + 2, acc.z);
        atomicAdd(yp + 3, acc.w);
    }
}

// ---------------------------------------------------------------------------
// Final: out += y[128,1024] @ W_comb[1024,512]  (bf16 MFMA, split-K 4, atomic)
// grid = (O/64, 4)
// ---------------------------------------------------------------------------
__global__ __launch_bounds__(256) void finalB(const float* __restrict__ ws,
                                              float* __restrict__ out) {
    __shared__ __align__(16) char smraw[(128 * 40 + 64 * 40) * 2];
    ushort* As = (ushort*)smraw;
    ushort* Bs = As + 128 * 40;
    const float* y = ws;
    const ushort* wc = (const ushort*)(ws + B_ * I_);
    const int n0 = blockIdx.x * 64, kbase = blockIdx.y * 256;
    const int tid = threadIdx.x, lane = tid & 63, w = tid >> 6, lo = lane & 15, hi = lane >> 4;

    float4v acc[2][4];
#pragma unroll
    for (int mf = 0; mf < 2; ++mf)
#pragma unroll
        for (int nf = 0; nf < 4; ++nf) acc[mf][nf] = (float4v){0.f, 0.f, 0.f, 0.f};

    for (int k0 = kbase; k0 < kbase + 256; k0 += 32) {
        {   // A tile from y (f32 -> bf16), stride I_
            const int row = tid >> 1, kh = (tid & 1) * 16;
            const float* ap = y + (size_t)row * I_ + k0 + kh;
#pragma unroll
            for (int j = 0; j < 4; ++j) {
                float4v v = *(const float4v*)(ap + 4 * j);
                short4v s;
                s[0] = (short)f2bf(v.x); s[1] = (short)f2bf(v.y);
                s[2] = (short)f2bf(v.z); s[3] = (short)f2bf(v.w);
                *(short4v*)&As[row * 40 + kh + 4 * j] = s;
            }
        }
        {   // B tile from W_comb (bf16 direct), stride O_
            const int k = tid >> 3, nq = (tid & 7) * 8;
            short8v bv = *(const short8v*)&wc[(size_t)(k0 + k) * O_ + n0 + nq];
#pragma unroll
            for (int c = 0; c < 8; ++c) Bs[(nq + c) * 40 + k] = (ushort)bv[c];
        }
        __syncthreads();
#pragma unroll
        for (int ks = 0; ks < 2; ++ks) {
            const int kk = ks * 16 + 4 * hi;
            short4v a[2], bfr[4];
#pragma unroll
            for (int mf = 0; mf < 2; ++mf)
                a[mf] = *(const short4v*)&As[(w * 32 + mf * 16 + lo) * 40 + kk];
#pragma unroll
            for (int nf = 0; nf < 4; ++nf)
                bfr[nf] = *(const short4v*)&Bs[(nf * 16 + lo) * 40 + kk];
#pragma unroll
            for (int mf = 0; mf < 2; ++mf)
#pragma unroll
                for (int nf = 0; nf < 4; ++nf) mfma16(acc[mf][nf], a[mf], bfr[nf]);
        }
        __syncthreads();
    }
#pragma unroll
    for (int mf = 0; mf < 2; ++mf)
#pragma unroll
        for (int nf = 0; nf < 4; ++nf)
#pragma unroll
            for (int i = 0; i < 4; ++i) {
                const int row = w * 32 + mf * 16 + hi * 4 + i;
                const int col = n0 + nf * 16 + lo;
                atomicAdd(&out[(size_t)row * O_ + col], acc[mf][nf][i]);
            }
}

// ---------------------------------------------------------------------------
extern "C" void kernel_launch(void* const* d_in, const int* in_sizes, int n_in,
                              void* d_out, int out_size, void* d_ws, size_t ws_size,
                              hipStream_t stream) {
    const float* x     = (const float*)d_in[0];
    const float* W_in  = (const float*)d_in[1];
    const float* b_in  = (const float*)d_in[2];
    const float* W_out = (const float*)d_in[3];
    const float* b_out = (const float*)d_in[4];
    float* out = (float*)d_out;
    float* ws  = (float*)d_ws;

    // wsum = sum_t (1-beta^(T-t))/(1-beta), exact in double on host
    const double beta = 0.9;
    const double bT = pow(beta, (double)T_);
    const float wsum = (float)(((double)T_ - beta * (1.0 - bT) / (1.0 - beta)) / (1.0 - beta));

    zero_y<<<B_ * I_ / 1024, 256, 0, stream>>>(ws);
    fusedA<<<64 + 8 + B_ * (T_ / 32), 256, 0, stream>>>(x, W_in, b_in, W_out, b_out, ws, out, wsum);
    finalB<<<dim3(O_ / 64, 4), 256, 0, stream>>>(ws, out);
}

// Round 7
// 115.690 us; speedup vs baseline: 1.1400x; 1.1400x over previous
//
#include <hip/hip_runtime.h>
#include <hip/hip_bf16.h>
#include <math.h>

// Problem dims (fixed by reference)
constexpr int B_ = 128, T_ = 512, I_ = 1024, H_ = 2048, O_ = 512;
#define BETA 0.9f

// ws float layout: w[512] | y[B*I] | Wcomb_f32[I*O]
constexpr int WOFF = 0;
constexpr int YOFF = 512;
constexpr int WCOFF = YOFF + B_ * I_;
constexpr int WS_FLOATS = WCOFF + I_ * O_;

typedef __attribute__((ext_vector_type(4))) short short4v;   // 4 bf16
typedef __attribute__((ext_vector_type(4))) float float4v;   // 4 f32

__device__ inline void mfma16(float4v& acc, short4v a, short4v b) {
    // D = A*B + C, classic CDNA 16x16x16 bf16 layout (R3-proven):
    //   A: row=l&15, k=4*(l>>4)+j ; B: col=l&15 ; D: col=l&15, row=4*(l>>4)+i
    asm("v_mfma_f32_16x16x16_bf16 %0, %1, %2, %0" : "+v"(acc) : "v"(a), "v"(b));
}

// ---------------------------------------------------------------------------
// Kernel 1: w[t] table; zero y and Wcomb
// ---------------------------------------------------------------------------
__global__ __launch_bounds__(256) void init_kernel(float* __restrict__ ws) {
    int idx = blockIdx.x * 256 + threadIdx.x;
    if (idx >= WS_FLOATS) return;
    if (idx < 512) {
        ws[idx] = (1.0f - powf(BETA, (float)(T_ - idx))) * (1.0f / (1.0f - BETA));
    } else {
        ws[idx] = 0.0f;   // y accumulator + Wcomb accumulator
    }
}

// ---------------------------------------------------------------------------
// Kernel 2 (R4-proven): out[r,c] = T*b_out[c] + wsum*(b_in @ W_out)[c]
// 8 blocks x 256 threads; each block owns 64 cols.
// ---------------------------------------------------------------------------
__global__ __launch_bounds__(256) void bias_kernel(const float* __restrict__ b_in,
                                                   const float* __restrict__ W_out,
                                                   const float* __restrict__ b_out,
                                                   float* __restrict__ out, float wsum) {
    __shared__ float red[256];
    __shared__ float bvl[64];
    const int c0 = blockIdx.x * 64;
    const int tid = threadIdx.x;
    const int cl = tid & 63, sl = tid >> 6;
    const int col = c0 + cl;
    float s = 0.f;
    const float* wp = W_out + (size_t)sl * 512 * O_ + col;
    for (int h = 0; h < 512; ++h) s += b_in[sl * 512 + h] * wp[(size_t)h * O_];
    red[sl * 64 + cl] = s;
    __syncthreads();
    if (tid < 64) {
        float tot = red[tid] + red[64 + tid] + red[128 + tid] + red[192 + tid];
        bvl[tid] = (float)T_ * b_out[c0 + tid] + wsum * tot;
    }
    __syncthreads();
    const float val = bvl[cl];
    for (int r = sl; r < B_; r += 4) out[(size_t)r * O_ + col] = val;
}

// ---------------------------------------------------------------------------
// Kernel 3 (R3-exact): y[b,i] += sum_{t in chunk} w[t] * x[b,t,i]
// grid = B * (T/32) = 2048 blocks.
// ---------------------------------------------------------------------------
constexpr int TCH = 32;
__global__ __launch_bounds__(256) void wreduce_kernel(const float* __restrict__ x,
                                                      float* __restrict__ ws) {
    __shared__ float wl[TCH];
    const int b  = blockIdx.x >> 4;   // T/TCH = 16 chunks
    const int tc = blockIdx.x & 15;
    const int t0 = tc * TCH;
    if (threadIdx.x < TCH) wl[threadIdx.x] = ws[WOFF + t0 + threadIdx.x];
    __syncthreads();

    const int i = threadIdx.x * 4;
    const float* xp = x + (size_t)b * T_ * I_ + (size_t)t0 * I_ + i;
    float4v acc = {0.f, 0.f, 0.f, 0.f};
#pragma unroll
    for (int tb = 0; tb < TCH; tb += 8) {
        float4v v[8];
#pragma unroll
        for (int j = 0; j < 8; ++j)
            v[j] = __builtin_nontemporal_load((const float4v*)(xp + (size_t)(tb + j) * I_));
#pragma unroll
        for (int j = 0; j < 8; ++j) {
            const float wt = wl[tb + j];
            acc.x += wt * v[j].x; acc.y += wt * v[j].y;
            acc.z += wt * v[j].z; acc.w += wt * v[j].w;
        }
    }
    float* yp = ws + YOFF + b * I_ + i;
    atomicAdd(yp + 0, acc.x);
    atomicAdd(yp + 1, acc.y);
    atomicAdd(yp + 2, acc.z);
    atomicAdd(yp + 3, acc.w);
}

// ---------------------------------------------------------------------------
// GEMM (R3 body, KCH=256 / 8 iters ONLY — other trip counts failed R5/R6):
// C[m0+0..127, N] += A[m0+0..127, K] @ B[K, N], bf16 MFMA, f32 atomicAdd.
// grid = (N/64, K/KCH, M/128); m0 = blockIdx.z*128.
// ---------------------------------------------------------------------------
template <int KGLOB, int NGLOB, int KCH>
__global__ __launch_bounds__(256) void mm128(const float* __restrict__ A,
                                             const float* __restrict__ Bm,
                                             float* __restrict__ C) {
    constexpr int BN = 64, BK = 32, PAD = 8;
    __shared__ __hip_bfloat16 As[128][BK + PAD];  // [row][k]
    __shared__ __hip_bfloat16 Bs[BN][BK + PAD];   // transposed: [n][k]

    const int n0    = blockIdx.x * BN;
    const int kbase = blockIdx.y * KCH;
    const int m0    = blockIdx.z * 128;
    const int tid   = threadIdx.x;
    const int lane  = tid & 63;
    const int w     = tid >> 6;       // wave id 0..3 -> rows [w*32, w*32+32)
    const int lo    = lane & 15;
    const int hi    = lane >> 4;

    float4v acc[2][4];
#pragma unroll
    for (int mf = 0; mf < 2; ++mf)
#pragma unroll
        for (int nf = 0; nf < 4; ++nf) acc[mf][nf] = (float4v){0.f, 0.f, 0.f, 0.f};

    for (int k0 = kbase; k0 < kbase + KCH; k0 += BK) {
        // --- stage A tile 128x32: thread -> row=tid>>1, half-k=(tid&1)*16
        {
            const int row = tid >> 1;
            const int kh  = (tid & 1) * 16;
            const float* ap = A + (size_t)(m0 + row) * KGLOB + k0 + kh;
#pragma unroll
            for (int j = 0; j < 4; ++j) {
                float4 v = *(const float4*)(ap + 4 * j);
                union { short4v s; __hip_bfloat16 h[4]; } u;
                u.h[0] = __float2bfloat16(v.x); u.h[1] = __float2bfloat16(v.y);
                u.h[2] = __float2bfloat16(v.z); u.h[3] = __float2bfloat16(v.w);
                *(short4v*)&As[row][kh + 4 * j] = u.s;
            }
        }
        // --- stage B tile 32x64 transposed: thread -> k=tid>>3, n-chunk=(tid&7)*8
        {
            const int k  = tid >> 3;
            const int nq = (tid & 7) * 8;
            const float* bp = Bm + (size_t)(k0 + k) * NGLOB + n0 + nq;
#pragma unroll
            for (int j = 0; j < 2; ++j) {
                float4 v = *(const float4*)(bp + 4 * j);
                Bs[nq + 4 * j + 0][k] = __float2bfloat16(v.x);
                Bs[nq + 4 * j + 1][k] = __float2bfloat16(v.y);
                Bs[nq + 4 * j + 2][k] = __float2bfloat16(v.z);
                Bs[nq + 4 * j + 3][k] = __float2bfloat16(v.w);
            }
        }
        __syncthreads();
#pragma unroll
        for (int ks = 0; ks < 2; ++ks) {
            const int kk = ks * 16 + 4 * hi;
            short4v a[2], bf[4];
#pragma unroll
            for (int mf = 0; mf < 2; ++mf)
                a[mf] = *(const short4v*)&As[w * 32 + mf * 16 + lo][kk];
#pragma unroll
            for (int nf = 0; nf < 4; ++nf)
                bf[nf] = *(const short4v*)&Bs[nf * 16 + lo][kk];
#pragma unroll
            for (int mf = 0; mf < 2; ++mf)
#pragma unroll
                for (int nf = 0; nf < 4; ++nf) mfma16(acc[mf][nf], a[mf], bf[nf]);
        }
        __syncthreads();
    }
    // --- epilogue: split-K atomic accumulate
#pragma unroll
    for (int mf = 0; mf < 2; ++mf)
#pragma unroll
        for (int nf = 0; nf < 4; ++nf)
#pragma unroll
            for (int i = 0; i < 4; ++i) {
                const int row = m0 + w * 32 + mf * 16 + hi * 4 + i;
                const int col = n0 + nf * 16 + lo;
                atomicAdd(&C[(size_t)row * NGLOB + col], acc[mf][nf][i]);
            }
}

// ---------------------------------------------------------------------------
extern "C" void kernel_launch(void* const* d_in, const int* in_sizes, int n_in,
                              void* d_out, int out_size, void* d_ws, size_t ws_size,
                              hipStream_t stream) {
    const float* x     = (const float*)d_in[0];
    const float* W_in  = (const float*)d_in[1];
    const float* b_in  = (const float*)d_in[2];
    const float* W_out = (const float*)d_in[3];
    const float* b_out = (const float*)d_in[4];
    float* out = (float*)d_out;
    float* ws  = (float*)d_ws;

    // wsum = sum_t (1-beta^(T-t))/(1-beta), exact in double on host
    const double beta = 0.9;
    const double bT = pow(beta, (double)T_);
    const float wsum = (float)(((double)T_ - beta * (1.0 - bT) / (1.0 - beta)) / (1.0 - beta));

    // 1) w table + zero accumulators
    init_kernel<<<(WS_FLOATS + 255) / 256, 256, 0, stream>>>(ws);

    // 2) out = T*b_out + wsum*(b_in @ W_out)   (f32 exact, R4-proven)
    bias_kernel<<<8, 256, 0, stream>>>(b_in, W_out, b_out, out, wsum);

    // 3) Wcomb(f32) = W_in[1024,2048] @ W_out[2048,512]
    //    grid (8 n-blocks, 8 k-splits, 8 m-blocks) = 512 blocks, 8 iters each
    mm128<H_, O_, 256><<<dim3(O_ / 64, H_ / 256, I_ / 128), 256, 0, stream>>>(W_in, W_out, ws + WCOFF);

    // 4) y[b,i] = sum_t w_t x[b,t,i]   (streams x, BW-bound)
    wreduce_kernel<<<B_ * (T_ / TCH), 256, 0, stream>>>(x, ws);

    // 5) out += y[128,1024] @ Wcomb[1024,512]
    //    grid (8 n-blocks, 4 k-splits) = 32 blocks, 8 iters each
    mm128<I_, O_, 256><<<dim3(O_ / 64, I_ / 256, 1), 256, 0, stream>>>(ws + YOFF, ws + WCOFF, out);
}

// Round 8
// 80.095 us; speedup vs baseline: 1.6466x; 1.4444x over previous
//
#include <hip/hip_runtime.h>
#include <hip/hip_bf16.h>
#include <math.h>

// Problem dims (fixed by reference)
constexpr int B_ = 128, T_ = 512, I_ = 1024, H_ = 2048, O_ = 512;
#define BETA 0.9f

// ws float layout: w[512] | y[B*I] | Z[B*H]
constexpr int WOFF = 0;
constexpr int YOFF = 512;
constexpr int ZOFF = YOFF + B_ * I_;
constexpr int WS_FLOATS = ZOFF + B_ * H_;

typedef __attribute__((ext_vector_type(4))) short short4v;   // 4 bf16
typedef __attribute__((ext_vector_type(8))) short short8v;   // 8 bf16 (4 VGPR)
typedef __attribute__((ext_vector_type(4))) float float4v;   // 4 f32

// ---------------------------------------------------------------------------
// Kernel 1: init w[t], zero y, Z = wsum*b_in, out = T*b_out
// ---------------------------------------------------------------------------
__global__ __launch_bounds__(256) void init_kernel(float* __restrict__ ws,
                                                   const float* __restrict__ b_in,
                                                   const float* __restrict__ b_out,
                                                   float* __restrict__ out, float wsum) {
    int idx = blockIdx.x * 256 + threadIdx.x;
    const int total = WS_FLOATS + B_ * O_;
    if (idx >= total) return;
    if (idx < 512) {
        ws[idx] = (1.0f - powf(BETA, (float)(T_ - idx))) * (1.0f / (1.0f - BETA));
    } else if (idx < ZOFF) {
        ws[idx] = 0.0f;                       // y accumulator
    } else if (idx < WS_FLOATS) {
        int j = idx - ZOFF;
        ws[idx] = wsum * b_in[j & (H_ - 1)];  // Z bias init
    } else {
        int j = idx - WS_FLOATS;
        out[j] = (float)T_ * b_out[j & (O_ - 1)];  // out bias init
    }
}

// ---------------------------------------------------------------------------
// Kernel 2: y[b,i] += sum_{t in chunk} w[t] * x[b,t,i]
// grid = B * (T/32) = 2048 blocks, 256 threads, thread -> float4 of I.
// Plain cached float4 loads (NT dropped — m13's BW ceiling used cached loads).
// ---------------------------------------------------------------------------
constexpr int TCH = 32;
__global__ __launch_bounds__(256) void wreduce_kernel(const float* __restrict__ x,
                                                      float* __restrict__ ws) {
    __shared__ float wl[TCH];
    const int b  = blockIdx.x >> 4;   // T/TCH = 16 chunks
    const int tc = blockIdx.x & 15;
    const int t0 = tc * TCH;
    if (threadIdx.x < TCH) wl[threadIdx.x] = ws[WOFF + t0 + threadIdx.x];
    __syncthreads();

    const int i = threadIdx.x * 4;
    const float* xp = x + (size_t)b * T_ * I_ + (size_t)t0 * I_ + i;
    float4v acc = {0.f, 0.f, 0.f, 0.f};
#pragma unroll
    for (int tb = 0; tb < TCH; tb += 8) {
        float4v v[8];
#pragma unroll
        for (int j = 0; j < 8; ++j)
            v[j] = *(const float4v*)(xp + (size_t)(tb + j) * I_);
#pragma unroll
        for (int j = 0; j < 8; ++j) {
            const float wt = wl[tb + j];
            acc.x += wt * v[j].x; acc.y += wt * v[j].y;
            acc.z += wt * v[j].z; acc.w += wt * v[j].w;
        }
    }
    float* yp = ws + YOFF + b * I_ + i;
    atomicAdd(yp + 0, acc.x);
    atomicAdd(yp + 1, acc.y);
    atomicAdd(yp + 2, acc.z);
    atomicAdd(yp + 3, acc.w);
}

// ---------------------------------------------------------------------------
// Kernel 3/4: C[128,N] += A[128,K] @ B[K,N], bf16 MFMA (BUILTIN, hazard-
// modeled), f32 atomic epilogue. 256 thr = 4 waves; BM=128, BN=64, BK=32.
// grid = (N/64, K/KCH). One mfma_f32_16x16x32_bf16 per fragment per BK tile.
//   A frag: row=l&15, k=(l>>4)*8+j (8 contiguous) ; B frag: col=l&15, same k
//   D frag: col=l&15, row=(l>>4)*4+reg            (m89/m91-verified)
// ---------------------------------------------------------------------------
template <int KGLOB, int NGLOB, int KCH>
__global__ __launch_bounds__(256) void mm128(const float* __restrict__ A,
                                             const float* __restrict__ Bm,
                                             float* __restrict__ C) {
    constexpr int BN = 64, BK = 32, PAD = 8;
    __shared__ __align__(16) __hip_bfloat16 As[128][BK + PAD];  // [row][k]
    __shared__ __align__(16) __hip_bfloat16 Bs[BN][BK + PAD];   // [n][k]

    const int n0    = blockIdx.x * BN;
    const int kbase = blockIdx.y * KCH;
    const int tid   = threadIdx.x;
    const int lane  = tid & 63;
    const int w     = tid >> 6;       // wave id 0..3 -> rows [w*32, w*32+32)
    const int lo    = lane & 15;
    const int hi    = lane >> 4;

    float4v acc[2][4];
#pragma unroll
    for (int mf = 0; mf < 2; ++mf)
#pragma unroll
        for (int nf = 0; nf < 4; ++nf) acc[mf][nf] = (float4v){0.f, 0.f, 0.f, 0.f};

    for (int k0 = kbase; k0 < kbase + KCH; k0 += BK) {
        // --- stage A tile 128x32: thread -> row=tid>>1, half-k=(tid&1)*16
        {
            const int row = tid >> 1;
            const int kh  = (tid & 1) * 16;
            const float* ap = A + (size_t)row * KGLOB + k0 + kh;
#pragma unroll
            for (int j = 0; j < 4; ++j) {
                float4 v = *(const float4*)(ap + 4 * j);
                union { short4v s; __hip_bfloat16 h[4]; } u;
                u.h[0] = __float2bfloat16(v.x); u.h[1] = __float2bfloat16(v.y);
                u.h[2] = __float2bfloat16(v.z); u.h[3] = __float2bfloat16(v.w);
                *(short4v*)&As[row][kh + 4 * j] = u.s;
            }
        }
        // --- stage B tile 32x64 transposed: thread -> k=tid>>3, n-chunk=(tid&7)*8
        {
            const int k  = tid >> 3;
            const int nq = (tid & 7) * 8;
            const float* bp = Bm + (size_t)(k0 + k) * NGLOB + n0 + nq;
#pragma unroll
            for (int j = 0; j < 2; ++j) {
                float4 v = *(const float4*)(bp + 4 * j);
                Bs[nq + 4 * j + 0][k] = __float2bfloat16(v.x);
                Bs[nq + 4 * j + 1][k] = __float2bfloat16(v.y);
                Bs[nq + 4 * j + 2][k] = __float2bfloat16(v.z);
                Bs[nq + 4 * j + 3][k] = __float2bfloat16(v.w);
            }
        }
        __syncthreads();
        {
            const int kk = hi * 8;   // lane's 8-wide k-group within BK=32
            short8v a[2], bv[4];
#pragma unroll
            for (int mf = 0; mf < 2; ++mf)
                a[mf] = *(const short8v*)&As[w * 32 + mf * 16 + lo][kk];
#pragma unroll
            for (int nf = 0; nf < 4; ++nf)
                bv[nf] = *(const short8v*)&Bs[nf * 16 + lo][kk];
#pragma unroll
            for (int mf = 0; mf < 2; ++mf)
#pragma unroll
                for (int nf = 0; nf < 4; ++nf)
                    acc[mf][nf] = __builtin_amdgcn_mfma_f32_16x16x32_bf16(
                        a[mf], bv[nf], acc[mf][nf], 0, 0, 0);
        }
        __syncthreads();
    }
    // --- epilogue: split-K atomic accumulate (C pre-initialized with bias)
#pragma unroll
    for (int mf = 0; mf < 2; ++mf)
#pragma unroll
        for (int nf = 0; nf < 4; ++nf)
#pragma unroll
            for (int i = 0; i < 4; ++i) {
                const int row = w * 32 + mf * 16 + hi * 4 + i;
                const int col = n0 + nf * 16 + lo;
                atomicAdd(&C[(size_t)row * NGLOB + col], acc[mf][nf][i]);
            }
}

// ---------------------------------------------------------------------------
extern "C" void kernel_launch(void* const* d_in, const int* in_sizes, int n_in,
                              void* d_out, int out_size, void* d_ws, size_t ws_size,
                              hipStream_t stream) {
    const float* x     = (const float*)d_in[0];
    const float* W_in  = (const float*)d_in[1];
    const float* b_in  = (const float*)d_in[2];
    const float* W_out = (const float*)d_in[3];
    const float* b_out = (const float*)d_in[4];
    float* out = (float*)d_out;
    float* ws  = (float*)d_ws;

    // wsum = sum_t (1-beta^(T-t))/(1-beta), exact in double on host
    const double beta = 0.9;
    const double bT = pow(beta, (double)T_);
    const float wsum = (float)(((double)T_ - beta * (1.0 - bT) / (1.0 - beta)) / (1.0 - beta));

    const int total = WS_FLOATS + B_ * O_;
    init_kernel<<<(total + 255) / 256, 256, 0, stream>>>(ws, b_in, b_out, out, wsum);

    wreduce_kernel<<<B_ * (T_ / TCH), 256, 0, stream>>>(x, ws);

    // Z = y @ W_in : K=1024, split-K 8 (KCH=128) -> 256 blocks, 4 iters each
    mm128<I_, H_, 128><<<dim3(H_ / 64, I_ / 128), 256, 0, stream>>>(ws + YOFF, W_in, ws + ZOFF);

    // out = Z @ W_out : K=2048, split-K 32 (KCH=64) -> 256 blocks, 2 iters each
    mm128<H_, O_, 64><<<dim3(O_ / 64, H_ / 64), 256, 0, stream>>>(ws + ZOFF, W_out, out);
}

// Round 9
// 73.637 us; speedup vs baseline: 1.7911x; 1.0877x over previous
//
#include <hip/hip_runtime.h>
#include <hip/hip_bf16.h>
#include <math.h>

// Problem dims (fixed by reference)
constexpr int B_ = 128, T_ = 512, I_ = 1024, H_ = 2048, O_ = 512;
#define BETA 0.9f

// ws float layout: w[512] | y[B*I] | Z[B*H]
constexpr int WOFF = 0;
constexpr int YOFF = 512;
constexpr int ZOFF = YOFF + B_ * I_;
constexpr int WS_FLOATS = ZOFF + B_ * H_;

typedef __attribute__((ext_vector_type(4))) short short4v;   // 4 bf16
typedef __attribute__((ext_vector_type(8))) short short8v;   // 8 bf16 (4 VGPR)
typedef __attribute__((ext_vector_type(4))) float float4v;   // 4 f32

// ---------------------------------------------------------------------------
// Kernel 1: init w[t], zero y, Z = wsum*b_in, out = T*b_out
// ---------------------------------------------------------------------------
__global__ __launch_bounds__(256) void init_kernel(float* __restrict__ ws,
                                                   const float* __restrict__ b_in,
                                                   const float* __restrict__ b_out,
                                                   float* __restrict__ out, float wsum) {
    int idx = blockIdx.x * 256 + threadIdx.x;
    const int total = WS_FLOATS + B_ * O_;
    if (idx >= total) return;
    if (idx < 512) {
        ws[idx] = (1.0f - powf(BETA, (float)(T_ - idx))) * (1.0f / (1.0f - BETA));
    } else if (idx < ZOFF) {
        ws[idx] = 0.0f;                       // y accumulator
    } else if (idx < WS_FLOATS) {
        int j = idx - ZOFF;
        ws[idx] = wsum * b_in[j & (H_ - 1)];  // Z bias init
    } else {
        int j = idx - WS_FLOATS;
        out[j] = (float)T_ * b_out[j & (O_ - 1)];  // out bias init
    }
}

// ---------------------------------------------------------------------------
// Kernel 2: y[b,i] += sum_{t in chunk} w[t] * x[b,t,i]
// TCH=128 -> grid = B*4 = 512 blocks (2/CU), 256 threads, thread -> float4 of I.
// 4-way atomic contention (was 16-way at TCH=32); 8-deep load batching.
// ---------------------------------------------------------------------------
constexpr int TCH = 128;
__global__ __launch_bounds__(256) void wreduce_kernel(const float* __restrict__ x,
                                                      float* __restrict__ ws) {
    __shared__ float wl[TCH];
    const int b  = blockIdx.x >> 2;   // T/TCH = 4 chunks
    const int tc = blockIdx.x & 3;
    const int t0 = tc * TCH;
    if (threadIdx.x < TCH) wl[threadIdx.x] = ws[WOFF + t0 + threadIdx.x];
    __syncthreads();

    const int i = threadIdx.x * 4;
    const float* xp = x + (size_t)b * T_ * I_ + (size_t)t0 * I_ + i;
    float4v acc = {0.f, 0.f, 0.f, 0.f};
#pragma unroll 4
    for (int tb = 0; tb < TCH; tb += 8) {
        float4v v[8];
#pragma unroll
        for (int j = 0; j < 8; ++j)
            v[j] = *(const float4v*)(xp + (size_t)(tb + j) * I_);
#pragma unroll
        for (int j = 0; j < 8; ++j) {
            const float wt = wl[tb + j];
            acc.x += wt * v[j].x; acc.y += wt * v[j].y;
            acc.z += wt * v[j].z; acc.w += wt * v[j].w;
        }
    }
    float* yp = ws + YOFF + b * I_ + i;
    atomicAdd(yp + 0, acc.x);
    atomicAdd(yp + 1, acc.y);
    atomicAdd(yp + 2, acc.z);
    atomicAdd(yp + 3, acc.w);
}

// ---------------------------------------------------------------------------
// Kernel 3/4: C[128,N] += A[128,K] @ B[K,N], bf16 MFMA (BUILTIN, hazard-
// modeled), f32 atomic epilogue. 256 thr = 4 waves; BM=128, BN=64, BK=32.
// grid = (N/64, K/KCH). One mfma_f32_16x16x32_bf16 per fragment per BK tile.
//   A frag: row=l&15, k=(l>>4)*8+j (8 contiguous) ; B frag: col=l&15, same k
//   D frag: col=l&15, row=(l>>4)*4+reg            (m89/m91-verified)
// ---------------------------------------------------------------------------
template <int KGLOB, int NGLOB, int KCH>
__global__ __launch_bounds__(256) void mm128(const float* __restrict__ A,
                                             const float* __restrict__ Bm,
                                             float* __restrict__ C) {
    constexpr int BN = 64, BK = 32, PAD = 8;
    __shared__ __align__(16) __hip_bfloat16 As[128][BK + PAD];  // [row][k]
    __shared__ __align__(16) __hip_bfloat16 Bs[BN][BK + PAD];   // [n][k]

    const int n0    = blockIdx.x * BN;
    const int kbase = blockIdx.y * KCH;
    const int tid   = threadIdx.x;
    const int lane  = tid & 63;
    const int w     = tid >> 6;       // wave id 0..3 -> rows [w*32, w*32+32)
    const int lo    = lane & 15;
    const int hi    = lane >> 4;

    float4v acc[2][4];
#pragma unroll
    for (int mf = 0; mf < 2; ++mf)
#pragma unroll
        for (int nf = 0; nf < 4; ++nf) acc[mf][nf] = (float4v){0.f, 0.f, 0.f, 0.f};

    for (int k0 = kbase; k0 < kbase + KCH; k0 += BK) {
        // --- stage A tile 128x32: thread -> row=tid>>1, half-k=(tid&1)*16
        {
            const int row = tid >> 1;
            const int kh  = (tid & 1) * 16;
            const float* ap = A + (size_t)row * KGLOB + k0 + kh;
#pragma unroll
            for (int j = 0; j < 4; ++j) {
                float4 v = *(const float4*)(ap + 4 * j);
                union { short4v s; __hip_bfloat16 h[4]; } u;
                u.h[0] = __float2bfloat16(v.x); u.h[1] = __float2bfloat16(v.y);
                u.h[2] = __float2bfloat16(v.z); u.h[3] = __float2bfloat16(v.w);
                *(short4v*)&As[row][kh + 4 * j] = u.s;
            }
        }
        // --- stage B tile 32x64 transposed: thread -> k=tid>>3, n-chunk=(tid&7)*8
        {
            const int k  = tid >> 3;
            const int nq = (tid & 7) * 8;
            const float* bp = Bm + (size_t)(k0 + k) * NGLOB + n0 + nq;
#pragma unroll
            for (int j = 0; j < 2; ++j) {
                float4 v = *(const float4*)(bp + 4 * j);
                Bs[nq + 4 * j + 0][k] = __float2bfloat16(v.x);
                Bs[nq + 4 * j + 1][k] = __float2bfloat16(v.y);
                Bs[nq + 4 * j + 2][k] = __float2bfloat16(v.z);
                Bs[nq + 4 * j + 3][k] = __float2bfloat16(v.w);
            }
        }
        __syncthreads();
        {
            const int kk = hi * 8;   // lane's 8-wide k-group within BK=32
            short8v a[2], bv[4];
#pragma unroll
            for (int mf = 0; mf < 2; ++mf)
                a[mf] = *(const short8v*)&As[w * 32 + mf * 16 + lo][kk];
#pragma unroll
            for (int nf = 0; nf < 4; ++nf)
                bv[nf] = *(const short8v*)&Bs[nf * 16 + lo][kk];
#pragma unroll
            for (int mf = 0; mf < 2; ++mf)
#pragma unroll
                for (int nf = 0; nf < 4; ++nf)
                    acc[mf][nf] = __builtin_amdgcn_mfma_f32_16x16x32_bf16(
                        a[mf], bv[nf], acc[mf][nf], 0, 0, 0);
        }
        __syncthreads();
    }
    // --- epilogue: split-K atomic accumulate (C pre-initialized with bias)
#pragma unroll
    for (int mf = 0; mf < 2; ++mf)
#pragma unroll
        for (int nf = 0; nf < 4; ++nf)
#pragma unroll
            for (int i = 0; i < 4; ++i) {
                const int row = w * 32 + mf * 16 + hi * 4 + i;
                const int col = n0 + nf * 16 + lo;
                atomicAdd(&C[(size_t)row * NGLOB + col], acc[mf][nf][i]);
            }
}

// ---------------------------------------------------------------------------
extern "C" void kernel_launch(void* const* d_in, const int* in_sizes, int n_in,
                              void* d_out, int out_size, void* d_ws, size_t ws_size,
                              hipStream_t stream) {
    const float* x     = (const float*)d_in[0];
    const float* W_in  = (const float*)d_in[1];
    const float* b_in  = (const float*)d_in[2];
    const float* W_out = (const float*)d_in[3];
    const float* b_out = (const float*)d_in[4];
    float* out = (float*)d_out;
    float* ws  = (float*)d_ws;

    // wsum = sum_t (1-beta^(T-t))/(1-beta), exact in double on host
    const double beta = 0.9;
    const double bT = pow(beta, (double)T_);
    const float wsum = (float)(((double)T_ - beta * (1.0 - bT) / (1.0 - beta)) / (1.0 - beta));

    const int total = WS_FLOATS + B_ * O_;
    init_kernel<<<(total + 255) / 256, 256, 0, stream>>>(ws, b_in, b_out, out, wsum);

    wreduce_kernel<<<B_ * (T_ / TCH), 256, 0, stream>>>(x, ws);

    // Z = y @ W_in : K=1024, split-K 8 (KCH=128) -> 256 blocks, 4 iters each
    mm128<I_, H_, 128><<<dim3(H_ / 64, I_ / 128), 256, 0, stream>>>(ws + YOFF, W_in, ws + ZOFF);

    // out = Z @ W_out : K=2048, split-K 32 (KCH=64) -> 256 blocks, 2 iters each
    mm128<H_, O_, 64><<<dim3(O_ / 64, H_ / 64), 256, 0, stream>>>(ws + ZOFF, W_out, out);
}